// Round 1
// baseline (421.460 us; speedup 1.0000x reference)
//
#include <hip/hip_runtime.h>

typedef unsigned short u16;
typedef unsigned int u32;
typedef __bf16 bf16x8 __attribute__((ext_vector_type(8)));
typedef float f32x4 __attribute__((ext_vector_type(4)));

__device__ __forceinline__ u16 f2b(float f) {
  u32 u = __float_as_uint(f);
  u32 r = (u + 0x7fffu + ((u >> 16) & 1u)) >> 16;
  return (u16)r;
}
__device__ __forceinline__ float b2f(u16 v) {
  return __uint_as_float(((u32)v) << 16);
}

// ---------------- fused fp32 -> bf16 cast of query, W_qkv, W_out ----------------
__global__ __launch_bounds__(256) void convert_all(
    const float4* __restrict__ q, const float4* __restrict__ w1,
    const float4* __restrict__ w2, ushort4* __restrict__ out) {
  int i = blockIdx.x * 256 + threadIdx.x;  // < 6291456
  float4 f;
  if (i < 2097152) f = q[i];
  else if (i < 5242880) f = w1[i - 2097152];
  else f = w2[i - 5242880];
  ushort4 o;
  o.x = f2b(f.x); o.y = f2b(f.y); o.z = f2b(f.z); o.w = f2b(f.w);
  out[i] = o;
}

// ---------------- RoPE cos/sin table: tab[l*64+dp] = (cos, sin) ----------------
__global__ __launch_bounds__(256) void rope_tab(float2* __restrict__ tab) {
  int idx = blockIdx.x * 256 + threadIdx.x;  // 131072 = 2048*64
  int l = idx >> 6, dp = idx & 63;
  float inv = exp2f(-(float)dp * 0.20762050593046869f);  // log2(10000)/64
  float ang = (float)l * inv;
  float s, c;
  sincosf(ang, &s, &c);
  tab[idx] = make_float2(c, s);
}

// ---------------- GEMM1: 256x256 tile, BK=64, 8 waves, 8-phase pipeline -------
// C[M=4096, N=6144] = A*W_qkv^T + bias. Each 256-col n-tile covers exactly two
// 128-col heads, handled as two sequential half-epilogues (RoPE for q/k heads,
// transposed store for v) staged through LDS at stride 129.
//
// Main loop: m201-style 8-phase schedule. LDS = 2 buffers x 4 half-tile slots
// (A0,A1,B0,B1; each 128x64 bf16 = 16 KB) = 128 KiB. Per K-tile t (4 phases):
//   P1: ds_read A0+B0 frags | stage B1(t+1) | bar | MFMA Q(0,0) | bar
//   P2: ds_read B1 frags    | stage A0(t+2) | bar | MFMA Q(0,1) | bar
//   P3: ds_read A1 frags    | stage B0(t+2) | bar | MFMA Q(1,1) | bar
//   P4: (bF0 kept in regs)  | stage A1(t+2) | vmcnt(6) | bar | MFMA Q(1,0) | bar
// Slot-recycle safety: every slot's last LDS read completes >=1 barrier pair
// before its overwriting global_load_lds is issued. vmcnt(6) = 3 half-tiles
// (the 3 newest stages for t+2) allowed in flight; guarantees all of t+1.
__global__ __launch_bounds__(512, 2) void gemm_qkv(
    const u16* __restrict__ A, const u16* __restrict__ B,
    const float* __restrict__ bias, const float2* __restrict__ tab,
    u16* __restrict__ qh, u16* __restrict__ kh, u16* __restrict__ vhT) {
  __shared__ __align__(16) u16 sh[65536];  // 128 KiB
  const int K = 2048;
  const int tid = threadIdx.x;
  const int lane = tid & 63;
  const int w = tid >> 6;
  const int fr = lane & 15;
  const int g = lane >> 4;

  // XCD-aware swizzle (384 blocks, 384 % 8 == 0 -> simple form is bijective)
  int wid = blockIdx.y * 24 + blockIdx.x;
  wid = (wid & 7) * 48 + (wid >> 3);
  const int m0 = (wid / 24) * 256;
  const int n0 = (wid % 24) * 256;

  const int sr = tid >> 3;                      // staging row in a 64-row round
  const int scb = ((tid & 7) ^ (sr & 7)) * 16;  // pre-swizzled global chunk (bytes)

  // stage one 128x64 half-tile (2 x global_load_lds dwordx4 per thread)
  auto STAGE = [&](const u16* src, int grow0, int k0, int slot) {
    const char* gp = (const char*)src + ((size_t)(grow0 + sr) * K + k0) * 2 + scb;
#pragma unroll
    for (int i = 0; i < 2; ++i)
      __builtin_amdgcn_global_load_lds(
          (__attribute__((address_space(1))) void*)(gp + (size_t)i * 64 * K * 2),
          (__attribute__((address_space(3))) void*)(sh + slot + i * 4096 + w * 512),
          16, 0, 0);
  };
  // A frags: wave owns rows (w&1)*64..+63 of the given 128-row half-slot
  auto LDA = [&](bf16x8 (&dst)[4][2], int slot) {
#pragma unroll
    for (int mi = 0; mi < 4; ++mi)
#pragma unroll
      for (int ks = 0; ks < 2; ++ks)
        __builtin_memcpy(&dst[mi][ks],
            &sh[slot + ((w & 1) * 64 + mi * 16 + fr) * 64 + (((ks * 4 + g) ^ (fr & 7)) * 8)],
            16);
  };
  // B frags: wave owns rows (w>>1)*32..+31 of the given 128-row half-slot
  auto LDB = [&](bf16x8 (&dst)[2][2], int slot) {
#pragma unroll
    for (int ni = 0; ni < 2; ++ni)
#pragma unroll
      for (int ks = 0; ks < 2; ++ks)
        __builtin_memcpy(&dst[ni][ks],
            &sh[slot + ((w >> 1) * 32 + ni * 16 + fr) * 64 + (((ks * 4 + g) ^ (fr & 7)) * 8)],
            16);
  };

  f32x4 acc[8][4] = {};
  auto MMA = [&](bf16x8 (&af)[4][2], bf16x8 (&bf)[2][2], int mo, int no) {
    __builtin_amdgcn_s_setprio(1);
#pragma unroll
    for (int ks = 0; ks < 2; ++ks)
#pragma unroll
      for (int mi = 0; mi < 4; ++mi)
#pragma unroll
        for (int ni = 0; ni < 2; ++ni)
          acc[mo + mi][no + ni] = __builtin_amdgcn_mfma_f32_16x16x32_bf16(
              af[mi][ks], bf[ni][ks], acc[mo + mi][no + ni], 0, 0, 0);
    __builtin_amdgcn_s_setprio(0);
  };

  // prologue: tile0 {A0,B0,A1,B1} + tile1 {A0,B0,A1}; wait tile0 (leave 3 half-tiles)
  STAGE(A, m0, 0, 0);
  STAGE(B, n0, 0, 16384);
  STAGE(A, m0 + 128, 0, 8192);
  STAGE(B, n0 + 128, 0, 24576);
  STAGE(A, m0, 64, 32768);
  STAGE(B, n0, 64, 32768 + 16384);
  STAGE(A, m0 + 128, 64, 32768 + 8192);
  asm volatile("s_waitcnt vmcnt(6)" ::: "memory");
  __builtin_amdgcn_s_barrier();

  for (int t = 0; t < 32; ++t) {
    const int buf = (t & 1) << 15;
    const int nbuf = buf ^ 32768;
    const int k2 = (t + 2) << 6;
    bf16x8 aF[4][2], bF0[2][2], bF1[2][2];

    // ---- P1 ----
    LDA(aF, buf);
    LDB(bF0, buf + 16384);
    if (t + 1 < 32) STAGE(B, n0 + 128, (t + 1) << 6, nbuf + 24576);
    __builtin_amdgcn_s_barrier();
    MMA(aF, bF0, 0, 0);
    __builtin_amdgcn_s_barrier();

    // ---- P2 ----
    LDB(bF1, buf + 24576);
    if (t + 2 < 32) STAGE(A, m0, k2, buf);
    __builtin_amdgcn_s_barrier();
    MMA(aF, bF1, 0, 2);
    __builtin_amdgcn_s_barrier();

    // ---- P3 ----
    LDA(aF, buf + 8192);
    if (t + 2 < 32) STAGE(B, n0, k2, buf + 16384);
    __builtin_amdgcn_s_barrier();
    MMA(aF, bF1, 4, 2);
    __builtin_amdgcn_s_barrier();

    // ---- P4 ---- (bF0 kept in registers; no LDS reads)
    if (t + 2 < 32) {
      STAGE(A, m0 + 128, k2, buf + 8192);
      asm volatile("s_waitcnt vmcnt(6)" ::: "memory");
    } else {
      asm volatile("s_waitcnt vmcnt(0)" ::: "memory");
    }
    __builtin_amdgcn_s_barrier();
    MMA(aF, bF0, 4, 0);
    __builtin_amdgcn_s_barrier();
  }

  // ---- epilogue: two 256x128 head-halves through LDS (stride 129) ----
  const int rq = g * 4;
  const int cq = fr;
#pragma unroll
  for (int nh = 0; nh < 2; ++nh) {
    __syncthreads();
#pragma unroll
    for (int m = 0; m < 8; ++m) {
#pragma unroll
      for (int nl = 0; nl < 2; ++nl) {
        const int n = nh * 2 + nl;
        const int c = (w >> 1) * 32 + nl * 16 + cq;
        const float bs = bias[n0 + nh * 128 + c];
        const int rb = (m >> 2) * 128 + (w & 1) * 64 + (m & 3) * 16 + rq;
#pragma unroll
        for (int i = 0; i < 4; ++i)
          sh[(rb + i) * 129 + c] = f2b(acc[m][n][i] + bs);
      }
    }
    __syncthreads();

    const int th = (n0 >> 7) + nh;  // 0..47: q(<16) k(<32) v
    const int h = th & 15;
    const int bq = m0 >> 11;
    const int l0 = m0 & 2047;
    const int bh = bq * 16 + h;

    if (th < 32) {
      const float qs2 = (th < 16) ? 0.08838834764831845f : 1.0f;
      u16* dst = (th < 16) ? qh : kh;
#pragma unroll 4
      for (int it = 0; it < 32; ++it) {
        int idx = it * 512 + tid;
        int l = idx >> 6, dp = idx & 63;
        float2 cs = tab[(size_t)(l0 + l) * 64 + dp];
        float x1 = b2f(sh[l * 129 + dp]);
        float x2 = b2f(sh[l * 129 + dp + 64]);
        size_t o = ((size_t)bh * 2048 + l0 + l) * 128;
        dst[o + dp]      = f2b((x1 * cs.x - x2 * cs.y) * qs2);
        dst[o + dp + 64] = f2b((x2 * cs.x + x1 * cs.y) * qs2);
      }
    } else {
#pragma unroll 4
      for (int it = 0; it < 32; ++it) {
        int idx = it * 512 + tid;
        int d = idx >> 7, l2 = (idx & 127) * 2;
        ushort2 t2;
        t2.x = sh[l2 * 129 + d];
        t2.y = sh[(l2 + 1) * 129 + d];
        *(ushort2*)(vhT + ((size_t)bh * 128 + d) * 2048 + l0 + l2) = t2;
      }
    }
  }
}

// ---------------- GEMM2: out[M,N] = A[M,K] * B[N,K]^T + bias (fp32 out) -------
__global__ __launch_bounds__(256) void gemm_bt(
    const u16* __restrict__ A, const u16* __restrict__ B,
    const float* __restrict__ bias, float* __restrict__ C,
    int M, int N, int K) {
  __shared__ __align__(16) u16 As[128 * 64];
  __shared__ __align__(16) u16 Bs[128 * 64];
  const int tid = threadIdx.x;
  const int lane = tid & 63;
  const int wave = tid >> 6;
  const int m0 = blockIdx.y * 128;
  const int n0 = blockIdx.x * 128;
  const int wm = (wave & 1) * 64;
  const int wn = (wave >> 1) * 64;
  f32x4 acc[4][4] = {};

  const int srow = wave * 32 + (lane >> 3);
  const int scb = ((lane & 7) ^ (lane >> 3)) * 16;
  const int fr = lane & 15;
  const int g = lane >> 4;

  const int kiters = K >> 6;
  for (int kt = 0; kt < kiters; ++kt) {
    const int k0 = kt << 6;
    __syncthreads();
    {
      const char* gA = (const char*)A + ((size_t)(m0 + srow) * K + k0) * 2 + scb;
      const char* gB = (const char*)B + ((size_t)(n0 + srow) * K + k0) * 2 + scb;
#pragma unroll
      for (int i = 0; i < 4; ++i) {
        __builtin_amdgcn_global_load_lds(
            (__attribute__((address_space(1))) void*)(gA + (size_t)i * 8 * K * 2),
            (__attribute__((address_space(3))) void*)(As + (wave * 32 + i * 8) * 64),
            16, 0, 0);
        __builtin_amdgcn_global_load_lds(
            (__attribute__((address_space(1))) void*)(gB + (size_t)i * 8 * K * 2),
            (__attribute__((address_space(3))) void*)(Bs + (wave * 32 + i * 8) * 64),
            16, 0, 0);
      }
    }
    __syncthreads();
#pragma unroll
    for (int ks = 0; ks < 2; ++ks) {
      const int so = ((ks * 4 + g) ^ (fr & 7)) * 8;
      bf16x8 aF[4], bF[4];
#pragma unroll
      for (int mi = 0; mi < 4; ++mi)
        __builtin_memcpy(&aF[mi], &As[(wm + mi * 16 + fr) * 64 + so], 16);
#pragma unroll
      for (int ni = 0; ni < 4; ++ni)
        __builtin_memcpy(&bF[ni], &Bs[(wn + ni * 16 + fr) * 64 + so], 16);
#pragma unroll
      for (int mi = 0; mi < 4; ++mi)
#pragma unroll
        for (int ni = 0; ni < 4; ++ni)
          acc[mi][ni] = __builtin_amdgcn_mfma_f32_16x16x32_bf16(aF[mi], bF[ni], acc[mi][ni], 0, 0, 0);
    }
  }
  const int rq = (lane >> 4) * 4;
  const int cq = lane & 15;
#pragma unroll
  for (int mi = 0; mi < 4; ++mi) {
#pragma unroll
    for (int ni = 0; ni < 4; ++ni) {
      int col = n0 + wn + ni * 16 + cq;
      float bs = bias[col];
#pragma unroll
      for (int i = 0; i < 4; ++i) {
        int row = m0 + wm + mi * 16 + rq + i;
        C[(size_t)row * N + col] = acc[mi][ni][i] + bs;
      }
    }
  }
}

// ---------------- causal flash attention, S^T orientation ----------------
__global__ __launch_bounds__(256, 2) void attn_flash(
    const u16* __restrict__ qh, const u16* __restrict__ kh,
    const u16* __restrict__ vhT, u16* __restrict__ oh) {
  __shared__ __align__(16) u16 Ks[64 * 128];
  __shared__ __align__(16) u16 Vt[128 * 64];
  __shared__ __align__(16) u16 Ps[128 * 72];
  const int tid = threadIdx.x;
  const int lane = tid & 63;
  const int w = tid >> 6;
  const int cq = lane & 15;
  const int g = lane >> 4;
  const int p = blockIdx.x;
  const int bh = blockIdx.y;
  const int b = bh >> 4, h = bh & 15;
  const int ktiles = 32 - p;
  int q0s[2];
  q0s[0] = p * 64;
  q0s[1] = (31 - p) * 64;

  bf16x8 qf[2][4];
#pragma unroll
  for (int s = 0; s < 2; ++s) {
    const u16* qp = qh + ((size_t)bh * 2048 + q0s[s] + w * 16 + cq) * 128 + g * 8;
#pragma unroll
    for (int ks = 0; ks < 4; ++ks)
      __builtin_memcpy(&qf[s][ks], qp + ks * 32, 16);
  }

  f32x4 o[2][8] = {};
  float mrow[2] = {-1e30f, -1e30f};
  float lrow[2] = {0.0f, 0.0f};

  const int krl = lane >> 4;
  const int kcl = lane & 15;
  const int vrl = lane >> 3;
  const int vcl = lane & 7;

  for (int kt = 0; kt < ktiles; ++kt) {
    __syncthreads();
    {
      const size_t kvb = (size_t)bh * 2048 + (size_t)kt * 64;
#pragma unroll
      for (int i = 0; i < 4; ++i) {
        int row = w * 16 + i * 4 + krl;
        int cgl = kcl ^ (row & 7);
        const char* src = (const char*)(kh + (kvb + row) * 128 + cgl * 8);
        __builtin_amdgcn_global_load_lds(
            (__attribute__((address_space(1))) void*)src,
            (__attribute__((address_space(3))) void*)(Ks + (w * 16 + i * 4) * 128),
            16, 0, 0);
      }
#pragma unroll
      for (int i = 0; i < 4; ++i) {
        int row = w * 32 + i * 8 + vrl;
        int cgl = vcl ^ (row & 7);
        const char* src =
            (const char*)(vhT + ((size_t)bh * 128 + row) * 2048 + kt * 64 + cgl * 8);
        __builtin_amdgcn_global_load_lds(
            (__attribute__((address_space(1))) void*)src,
            (__attribute__((address_space(3))) void*)(Vt + (w * 32 + i * 8) * 64),
            16, 0, 0);
      }
    }
    __syncthreads();

    const bool nA = (kt <= p);
    f32x4 S[4][2] = {};
    __builtin_amdgcn_s_setprio(1);
#pragma unroll
    for (int ks = 0; ks < 4; ++ks) {
#pragma unroll
      for (int mt = 0; mt < 4; ++mt) {
        bf16x8 kf;
        int slot = (ks * 4 + g) ^ (cq & 7);
        __builtin_memcpy(&kf, &Ks[(mt * 16 + cq) * 128 + slot * 8], 16);
        if (nA)
          S[mt][0] = __builtin_amdgcn_mfma_f32_16x16x32_bf16(kf, qf[0][ks], S[mt][0], 0, 0, 0);
        S[mt][1] = __builtin_amdgcn_mfma_f32_16x16x32_bf16(kf, qf[1][ks], S[mt][1], 0, 0, 0);
      }
    }
    __builtin_amdgcn_s_setprio(0);

#pragma unroll
    for (int s = 0; s < 2; ++s) {
      if (s == 0 && !nA) continue;
      const int dtile = s ? (ktiles - 1) : p;
      if (kt == dtile) {
        const int qg = q0s[s] + w * 16 + cq;
#pragma unroll
        for (int mt = 0; mt < 4; ++mt)
#pragma unroll
          for (int i = 0; i < 4; ++i)
            if (kt * 64 + mt * 16 + g * 4 + i > qg) S[mt][s][i] = -1e30f;
      }
      float mx = S[0][s][0];
#pragma unroll
      for (int mt = 0; mt < 4; ++mt)
#pragma unroll
        for (int i = 0; i < 4; ++i) mx = fmaxf(mx, S[mt][s][i]);
      mx = fmaxf(mx, __shfl_xor(mx, 16));
      mx = fmaxf(mx, __shfl_xor(mx, 32));
      float mnew = fmaxf(mrow[s], mx);
      float al = __expf(mrow[s] - mnew);
      mrow[s] = mnew;
      float rs = 0.0f;
#pragma unroll
      for (int mt = 0; mt < 4; ++mt) {
        float e0 = __expf(S[mt][s][0] - mnew);
        float e1 = __expf(S[mt][s][1] - mnew);
        float e2 = __expf(S[mt][s][2] - mnew);
        float e3 = __expf(S[mt][s][3] - mnew);
        rs += (e0 + e1) + (e2 + e3);
        ushort4 pk;
        pk.x = f2b(e0); pk.y = f2b(e1); pk.z = f2b(e2); pk.w = f2b(e3);
        *(ushort4*)&Ps[(s * 64 + w * 16 + cq) * 72 + mt * 16 + g * 4] = pk;
      }
      rs += __shfl_xor(rs, 16);
      rs += __shfl_xor(rs, 32);
      lrow[s] = lrow[s] * al + rs;
#pragma unroll
      for (int dmt = 0; dmt < 8; ++dmt) {
        o[s][dmt][0] *= al; o[s][dmt][1] *= al;
        o[s][dmt][2] *= al; o[s][dmt][3] *= al;
      }
    }

    __builtin_amdgcn_s_setprio(1);
#pragma unroll
    for (int ks = 0; ks < 2; ++ks) {
      bf16x8 pf0, pf1;
      if (nA) __builtin_memcpy(&pf0, &Ps[(w * 16 + cq) * 72 + ks * 32 + g * 8], 16);
      __builtin_memcpy(&pf1, &Ps[(64 + w * 16 + cq) * 72 + ks * 32 + g * 8], 16);
#pragma unroll
      for (int dmt = 0; dmt < 8; ++dmt) {
        bf16x8 vf;
        int slot = (ks * 4 + g) ^ (cq & 7);
        __builtin_memcpy(&vf, &Vt[(dmt * 16 + cq) * 64 + slot * 8], 16);
        if (nA)
          o[0][dmt] = __builtin_amdgcn_mfma_f32_16x16x32_bf16(vf, pf0, o[0][dmt], 0, 0, 0);
        o[1][dmt] = __builtin_amdgcn_mfma_f32_16x16x32_bf16(vf, pf1, o[1][dmt], 0, 0, 0);
      }
    }
    __builtin_amdgcn_s_setprio(0);
  }

#pragma unroll
  for (int s = 0; s < 2; ++s) {
    float inv = 1.0f / lrow[s];
    int qg = q0s[s] + w * 16 + cq;
    size_t base = ((size_t)(b * 2048 + qg)) * 2048 + h * 128;
#pragma unroll
    for (int dmt = 0; dmt < 8; ++dmt) {
      ushort4 t;
      t.x = f2b(o[s][dmt][0] * inv);
      t.y = f2b(o[s][dmt][1] * inv);
      t.z = f2b(o[s][dmt][2] * inv);
      t.w = f2b(o[s][dmt][3] * inv);
      *(ushort4*)(oh + base + dmt * 16 + g * 4) = t;
    }
  }
}

extern "C" void kernel_launch(void* const* d_in, const int* in_sizes, int n_in,
                              void* d_out, int out_size, void* d_ws, size_t ws_size,
                              hipStream_t stream) {
  (void)in_sizes; (void)n_in; (void)out_size; (void)ws_size;
  const float* query = (const float*)d_in[0];
  const float* W_qkv = (const float*)d_in[1];
  const float* b_qkv = (const float*)d_in[2];
  const float* W_out = (const float*)d_in[3];
  const float* b_out = (const float*)d_in[4];
  float* out = (float*)d_out;
  char* ws = (char*)d_ws;

  u16*    Abf  = (u16*)(ws + 0);                    // 16 MB  query bf16
  u16*    W1bf = (u16*)(ws + (size_t)16777216);     // 24 MB  W_qkv bf16
  u16*    W2bf = (u16*)(ws + (size_t)41943040);     //  8 MB  W_out bf16
  u16*    qhp  = (u16*)(ws + (size_t)50331648);     // 16 MB  (B*H,L,128) pre-scaled
  u16*    khp  = (u16*)(ws + (size_t)67108864);     // 16 MB  (B*H,L,128)
  u16*    vhT  = (u16*)(ws + (size_t)83886080);     // 16 MB  (B*H,128,L)
  u16*    ohp  = (u16*)(ws + (size_t)100663296);    // 16 MB  attn out (B,L,2048)
  float2* tab  = (float2*)(ws + (size_t)117440512); //  1 MB  rope cos/sin

  convert_all<<<24576, 256, 0, stream>>>((const float4*)query, (const float4*)W_qkv,
                                         (const float4*)W_out, (ushort4*)ws);
  rope_tab<<<512, 256, 0, stream>>>(tab);
  gemm_qkv<<<dim3(24, 16), 512, 0, stream>>>(Abf, W1bf, b_qkv, tab, qhp, khp, vhT);
  attn_flash<<<dim3(16, 32), 256, 0, stream>>>(qhp, khp, vhT, ohp);
  gemm_bt<<<dim3(16, 32), 256, 0, stream>>>(ohp, W2bf, b_out, out, 4096, 2048, 2048);
}

// Round 2
// 416.387 us; speedup vs baseline: 1.0122x; 1.0122x over previous
//
#include <hip/hip_runtime.h>

typedef unsigned short u16;
typedef unsigned int u32;
typedef __bf16 bf16x8 __attribute__((ext_vector_type(8)));
typedef float f32x4 __attribute__((ext_vector_type(4)));

__device__ __forceinline__ u16 f2b(float f) {
  u32 u = __float_as_uint(f);
  u32 r = (u + 0x7fffu + ((u >> 16) & 1u)) >> 16;
  return (u16)r;
}
__device__ __forceinline__ float b2f(u16 v) {
  return __uint_as_float(((u32)v) << 16);
}

// ---------------- fused fp32 -> bf16 cast of query, W_qkv, W_out ----------------
__global__ __launch_bounds__(256) void convert_all(
    const float4* __restrict__ q, const float4* __restrict__ w1,
    const float4* __restrict__ w2, ushort4* __restrict__ out) {
  int i = blockIdx.x * 256 + threadIdx.x;  // < 6291456
  float4 f;
  if (i < 2097152) f = q[i];
  else if (i < 5242880) f = w1[i - 2097152];
  else f = w2[i - 5242880];
  ushort4 o;
  o.x = f2b(f.x); o.y = f2b(f.y); o.z = f2b(f.z); o.w = f2b(f.w);
  out[i] = o;
}

// ---------------- RoPE cos/sin table: tab[l*64+dp] = (cos, sin) ----------------
__global__ __launch_bounds__(256) void rope_tab(float2* __restrict__ tab) {
  int idx = blockIdx.x * 256 + threadIdx.x;  // 131072 = 2048*64
  int l = idx >> 6, dp = idx & 63;
  float inv = exp2f(-(float)dp * 0.20762050593046869f);  // log2(10000)/64
  float ang = (float)l * inv;
  float s, c;
  sincosf(ang, &s, &c);
  tab[idx] = make_float2(c, s);
}

// ---------------- GEMM1: 256x256 tile, BK=64, 8 waves, 8-phase pipeline -------
// C[M=4096, N=6144] = A*W_qkv^T + bias. Identity block mapping: with grid
// (24,16), round-robin XCD assignment gives each XCD columns {x, x+8, x+16}
// -> 3 MB B-panel footprint per XCD L2 (fits 4 MiB). No explicit swizzle.
//
// Phase pinning (the round-1 failure): raw s_barrier is NOT a compiler fence;
// each phase is pinned with "memory"-clobbered waitcnt asm + sched_barrier(0)
// so hipcc cannot dissolve the interleave. vmcnt(6) = 3 half-tiles in flight.
__global__ __launch_bounds__(512, 2) void gemm_qkv(
    const u16* __restrict__ A, const u16* __restrict__ B,
    const float* __restrict__ bias, const float2* __restrict__ tab,
    u16* __restrict__ qh, u16* __restrict__ kh, u16* __restrict__ vhT) {
  __shared__ __align__(16) u16 sh[65536];  // 128 KiB
  const int K = 2048;
  const int tid = threadIdx.x;
  const int lane = tid & 63;
  const int w = tid >> 6;
  const int fr = lane & 15;
  const int g = lane >> 4;

  const int m0 = blockIdx.y * 256;
  const int n0 = blockIdx.x * 256;

  const int sr = tid >> 3;                      // staging row in a 64-row round
  const int scb = ((tid & 7) ^ (sr & 7)) * 16;  // pre-swizzled global chunk (bytes)

  // stage one 128x64 half-tile (2 x global_load_lds dwordx4 per thread)
  auto STAGE = [&](const u16* src, int grow0, int k0, int slot) {
    const char* gp = (const char*)src + ((size_t)(grow0 + sr) * K + k0) * 2 + scb;
#pragma unroll
    for (int i = 0; i < 2; ++i)
      __builtin_amdgcn_global_load_lds(
          (__attribute__((address_space(1))) void*)(gp + (size_t)i * 64 * K * 2),
          (__attribute__((address_space(3))) void*)(sh + slot + i * 4096 + w * 512),
          16, 0, 0);
  };
  // A frags: wave owns rows (w&1)*64..+63 of the given 128-row half-slot
  auto LDA = [&](bf16x8 (&dst)[4][2], int slot) {
#pragma unroll
    for (int mi = 0; mi < 4; ++mi)
#pragma unroll
      for (int ks = 0; ks < 2; ++ks)
        __builtin_memcpy(&dst[mi][ks],
            &sh[slot + ((w & 1) * 64 + mi * 16 + fr) * 64 + (((ks * 4 + g) ^ (fr & 7)) * 8)],
            16);
  };
  // B frags: wave owns rows (w>>1)*32..+31 of the given 128-row half-slot
  auto LDB = [&](bf16x8 (&dst)[2][2], int slot) {
#pragma unroll
    for (int ni = 0; ni < 2; ++ni)
#pragma unroll
      for (int ks = 0; ks < 2; ++ks)
        __builtin_memcpy(&dst[ni][ks],
            &sh[slot + ((w >> 1) * 32 + ni * 16 + fr) * 64 + (((ks * 4 + g) ^ (fr & 7)) * 8)],
            16);
  };

  f32x4 acc[8][4] = {};
  auto MMA = [&](bf16x8 (&af)[4][2], bf16x8 (&bf)[2][2], int mo, int no) {
    __builtin_amdgcn_s_setprio(1);
#pragma unroll
    for (int ks = 0; ks < 2; ++ks)
#pragma unroll
      for (int mi = 0; mi < 4; ++mi)
#pragma unroll
        for (int ni = 0; ni < 2; ++ni)
          acc[mo + mi][no + ni] = __builtin_amdgcn_mfma_f32_16x16x32_bf16(
              af[mi][ks], bf[ni][ks], acc[mo + mi][no + ni], 0, 0, 0);
    __builtin_amdgcn_s_setprio(0);
  };

  // prologue: tile0 {A0,B0,A1,B1} + tile1 {A0,B0,A1}; wait to 6 outstanding
  // (completes all of tile0; leaves tile1's 3 half-tiles in flight)
  STAGE(A, m0, 0, 0);
  STAGE(B, n0, 0, 16384);
  STAGE(A, m0 + 128, 0, 8192);
  STAGE(B, n0 + 128, 0, 24576);
  STAGE(A, m0, 64, 32768);
  STAGE(B, n0, 64, 32768 + 16384);
  STAGE(A, m0 + 128, 64, 32768 + 8192);
  asm volatile("s_waitcnt vmcnt(6)" ::: "memory");
  __builtin_amdgcn_s_barrier();

  for (int t = 0; t < 32; ++t) {
    const int buf = (t & 1) << 15;
    const int nbuf = buf ^ 32768;
    const int k2 = (t + 2) << 6;
    bf16x8 aF[4][2], bF0[2][2], bF1[2][2];

    // ---- P1 ----
    LDA(aF, buf);
    LDB(bF0, buf + 16384);
    if (t + 1 < 32) STAGE(B, n0 + 128, (t + 1) << 6, nbuf + 24576);
    __builtin_amdgcn_s_barrier();
    asm volatile("s_waitcnt lgkmcnt(0)" ::: "memory");
    __builtin_amdgcn_sched_barrier(0);
    MMA(aF, bF0, 0, 0);
    asm volatile("" ::: "memory");
    __builtin_amdgcn_s_barrier();

    // ---- P2 ----
    LDB(bF1, buf + 24576);
    if (t + 2 < 32) STAGE(A, m0, k2, buf);
    __builtin_amdgcn_s_barrier();
    asm volatile("s_waitcnt lgkmcnt(0)" ::: "memory");
    __builtin_amdgcn_sched_barrier(0);
    MMA(aF, bF1, 0, 2);
    asm volatile("" ::: "memory");
    __builtin_amdgcn_s_barrier();

    // ---- P3 ----
    LDA(aF, buf + 8192);
    if (t + 2 < 32) STAGE(B, n0, k2, buf + 16384);
    __builtin_amdgcn_s_barrier();
    asm volatile("s_waitcnt lgkmcnt(0)" ::: "memory");
    __builtin_amdgcn_sched_barrier(0);
    MMA(aF, bF1, 4, 2);
    asm volatile("" ::: "memory");
    __builtin_amdgcn_s_barrier();

    // ---- P4 ---- (bF0 kept in registers; no LDS reads this phase)
    if (t + 2 < 32) {
      STAGE(A, m0 + 128, k2, buf + 8192);
      asm volatile("s_waitcnt vmcnt(6)" ::: "memory");
    } else {
      asm volatile("s_waitcnt vmcnt(0)" ::: "memory");
    }
    __builtin_amdgcn_s_barrier();
    __builtin_amdgcn_sched_barrier(0);
    MMA(aF, bF0, 4, 0);
    asm volatile("" ::: "memory");
    __builtin_amdgcn_s_barrier();
  }

  // ---- epilogue: two 256x128 head-halves through LDS (stride 129) ----
  const int rq = g * 4;
  const int cq = fr;
#pragma unroll
  for (int nh = 0; nh < 2; ++nh) {
    __syncthreads();
#pragma unroll
    for (int m = 0; m < 8; ++m) {
#pragma unroll
      for (int nl = 0; nl < 2; ++nl) {
        const int n = nh * 2 + nl;
        const int c = (w >> 1) * 32 + nl * 16 + cq;
        const float bs = bias[n0 + nh * 128 + c];
        const int rb = (m >> 2) * 128 + (w & 1) * 64 + (m & 3) * 16 + rq;
#pragma unroll
        for (int i = 0; i < 4; ++i)
          sh[(rb + i) * 129 + c] = f2b(acc[m][n][i] + bs);
      }
    }
    __syncthreads();

    const int th = (n0 >> 7) + nh;  // 0..47: q(<16) k(<32) v
    const int h = th & 15;
    const int bq = m0 >> 11;
    const int l0 = m0 & 2047;
    const int bh = bq * 16 + h;

    if (th < 32) {
      const float qs2 = (th < 16) ? 0.08838834764831845f : 1.0f;
      u16* dst = (th < 16) ? qh : kh;
#pragma unroll 4
      for (int it = 0; it < 32; ++it) {
        int idx = it * 512 + tid;
        int l = idx >> 6, dp = idx & 63;
        float2 cs = tab[(size_t)(l0 + l) * 64 + dp];
        float x1 = b2f(sh[l * 129 + dp]);
        float x2 = b2f(sh[l * 129 + dp + 64]);
        size_t o = ((size_t)bh * 2048 + l0 + l) * 128;
        dst[o + dp]      = f2b((x1 * cs.x - x2 * cs.y) * qs2);
        dst[o + dp + 64] = f2b((x2 * cs.x + x1 * cs.y) * qs2);
      }
    } else {
#pragma unroll 4
      for (int it = 0; it < 32; ++it) {
        int idx = it * 512 + tid;
        int d = idx >> 7, l2 = (idx & 127) * 2;
        ushort2 t2;
        t2.x = sh[l2 * 129 + d];
        t2.y = sh[(l2 + 1) * 129 + d];
        *(ushort2*)(vhT + ((size_t)bh * 128 + d) * 2048 + l0 + l2) = t2;
      }
    }
  }
}

// ---------------- GEMM2: out[M,N] = A[M,K] * B[N,K]^T + bias (fp32 out) -------
__global__ __launch_bounds__(256) void gemm_bt(
    const u16* __restrict__ A, const u16* __restrict__ B,
    const float* __restrict__ bias, float* __restrict__ C,
    int M, int N, int K) {
  __shared__ __align__(16) u16 As[128 * 64];
  __shared__ __align__(16) u16 Bs[128 * 64];
  const int tid = threadIdx.x;
  const int lane = tid & 63;
  const int wave = tid >> 6;
  const int m0 = blockIdx.y * 128;
  const int n0 = blockIdx.x * 128;
  const int wm = (wave & 1) * 64;
  const int wn = (wave >> 1) * 64;
  f32x4 acc[4][4] = {};

  const int srow = wave * 32 + (lane >> 3);
  const int scb = ((lane & 7) ^ (lane >> 3)) * 16;
  const int fr = lane & 15;
  const int g = lane >> 4;

  const int kiters = K >> 6;
  for (int kt = 0; kt < kiters; ++kt) {
    const int k0 = kt << 6;
    __syncthreads();
    {
      const char* gA = (const char*)A + ((size_t)(m0 + srow) * K + k0) * 2 + scb;
      const char* gB = (const char*)B + ((size_t)(n0 + srow) * K + k0) * 2 + scb;
#pragma unroll
      for (int i = 0; i < 4; ++i) {
        __builtin_amdgcn_global_load_lds(
            (__attribute__((address_space(1))) void*)(gA + (size_t)i * 8 * K * 2),
            (__attribute__((address_space(3))) void*)(As + (wave * 32 + i * 8) * 64),
            16, 0, 0);
        __builtin_amdgcn_global_load_lds(
            (__attribute__((address_space(1))) void*)(gB + (size_t)i * 8 * K * 2),
            (__attribute__((address_space(3))) void*)(Bs + (wave * 32 + i * 8) * 64),
            16, 0, 0);
      }
    }
    __syncthreads();
#pragma unroll
    for (int ks = 0; ks < 2; ++ks) {
      const int so = ((ks * 4 + g) ^ (fr & 7)) * 8;
      bf16x8 aF[4], bF[4];
#pragma unroll
      for (int mi = 0; mi < 4; ++mi)
        __builtin_memcpy(&aF[mi], &As[(wm + mi * 16 + fr) * 64 + so], 16);
#pragma unroll
      for (int ni = 0; ni < 4; ++ni)
        __builtin_memcpy(&bF[ni], &Bs[(wn + ni * 16 + fr) * 64 + so], 16);
#pragma unroll
      for (int mi = 0; mi < 4; ++mi)
#pragma unroll
        for (int ni = 0; ni < 4; ++ni)
          acc[mi][ni] = __builtin_amdgcn_mfma_f32_16x16x32_bf16(aF[mi], bF[ni], acc[mi][ni], 0, 0, 0);
    }
  }
  const int rq = (lane >> 4) * 4;
  const int cq = lane & 15;
#pragma unroll
  for (int mi = 0; mi < 4; ++mi) {
#pragma unroll
    for (int ni = 0; ni < 4; ++ni) {
      int col = n0 + wn + ni * 16 + cq;
      float bs = bias[col];
#pragma unroll
      for (int i = 0; i < 4; ++i) {
        int row = m0 + wm + mi * 16 + rq + i;
        C[(size_t)row * N + col] = acc[mi][ni][i] + bs;
      }
    }
  }
}

// ---------------- causal flash attention, S^T orientation ----------------
__global__ __launch_bounds__(256, 2) void attn_flash(
    const u16* __restrict__ qh, const u16* __restrict__ kh,
    const u16* __restrict__ vhT, u16* __restrict__ oh) {
  __shared__ __align__(16) u16 Ks[64 * 128];
  __shared__ __align__(16) u16 Vt[128 * 64];
  __shared__ __align__(16) u16 Ps[128 * 72];
  const int tid = threadIdx.x;
  const int lane = tid & 63;
  const int w = tid >> 6;
  const int cq = lane & 15;
  const int g = lane >> 4;
  const int p = blockIdx.x;
  const int bh = blockIdx.y;
  const int b = bh >> 4, h = bh & 15;
  const int ktiles = 32 - p;
  int q0s[2];
  q0s[0] = p * 64;
  q0s[1] = (31 - p) * 64;

  bf16x8 qf[2][4];
#pragma unroll
  for (int s = 0; s < 2; ++s) {
    const u16* qp = qh + ((size_t)bh * 2048 + q0s[s] + w * 16 + cq) * 128 + g * 8;
#pragma unroll
    for (int ks = 0; ks < 4; ++ks)
      __builtin_memcpy(&qf[s][ks], qp + ks * 32, 16);
  }

  f32x4 o[2][8] = {};
  float mrow[2] = {-1e30f, -1e30f};
  float lrow[2] = {0.0f, 0.0f};

  const int krl = lane >> 4;
  const int kcl = lane & 15;
  const int vrl = lane >> 3;
  const int vcl = lane & 7;

  for (int kt = 0; kt < ktiles; ++kt) {
    __syncthreads();
    {
      const size_t kvb = (size_t)bh * 2048 + (size_t)kt * 64;
#pragma unroll
      for (int i = 0; i < 4; ++i) {
        int row = w * 16 + i * 4 + krl;
        int cgl = kcl ^ (row & 7);
        const char* src = (const char*)(kh + (kvb + row) * 128 + cgl * 8);
        __builtin_amdgcn_global_load_lds(
            (__attribute__((address_space(1))) void*)src,
            (__attribute__((address_space(3))) void*)(Ks + (w * 16 + i * 4) * 128),
            16, 0, 0);
      }
#pragma unroll
      for (int i = 0; i < 4; ++i) {
        int row = w * 32 + i * 8 + vrl;
        int cgl = vcl ^ (row & 7);
        const char* src =
            (const char*)(vhT + ((size_t)bh * 128 + row) * 2048 + kt * 64 + cgl * 8);
        __builtin_amdgcn_global_load_lds(
            (__attribute__((address_space(1))) void*)src,
            (__attribute__((address_space(3))) void*)(Vt + (w * 32 + i * 8) * 64),
            16, 0, 0);
      }
    }
    __syncthreads();

    const bool nA = (kt <= p);
    f32x4 S[4][2] = {};
    __builtin_amdgcn_s_setprio(1);
#pragma unroll
    for (int ks = 0; ks < 4; ++ks) {
#pragma unroll
      for (int mt = 0; mt < 4; ++mt) {
        bf16x8 kf;
        int slot = (ks * 4 + g) ^ (cq & 7);
        __builtin_memcpy(&kf, &Ks[(mt * 16 + cq) * 128 + slot * 8], 16);
        if (nA)
          S[mt][0] = __builtin_amdgcn_mfma_f32_16x16x32_bf16(kf, qf[0][ks], S[mt][0], 0, 0, 0);
        S[mt][1] = __builtin_amdgcn_mfma_f32_16x16x32_bf16(kf, qf[1][ks], S[mt][1], 0, 0, 0);
      }
    }
    __builtin_amdgcn_s_setprio(0);

#pragma unroll
    for (int s = 0; s < 2; ++s) {
      if (s == 0 && !nA) continue;
      const int dtile = s ? (ktiles - 1) : p;
      if (kt == dtile) {
        const int qg = q0s[s] + w * 16 + cq;
#pragma unroll
        for (int mt = 0; mt < 4; ++mt)
#pragma unroll
          for (int i = 0; i < 4; ++i)
            if (kt * 64 + mt * 16 + g * 4 + i > qg) S[mt][s][i] = -1e30f;
      }
      float mx = S[0][s][0];
#pragma unroll
      for (int mt = 0; mt < 4; ++mt)
#pragma unroll
        for (int i = 0; i < 4; ++i) mx = fmaxf(mx, S[mt][s][i]);
      mx = fmaxf(mx, __shfl_xor(mx, 16));
      mx = fmaxf(mx, __shfl_xor(mx, 32));
      float mnew = fmaxf(mrow[s], mx);
      float al = __expf(mrow[s] - mnew);
      mrow[s] = mnew;
      float rs = 0.0f;
#pragma unroll
      for (int mt = 0; mt < 4; ++mt) {
        float e0 = __expf(S[mt][s][0] - mnew);
        float e1 = __expf(S[mt][s][1] - mnew);
        float e2 = __expf(S[mt][s][2] - mnew);
        float e3 = __expf(S[mt][s][3] - mnew);
        rs += (e0 + e1) + (e2 + e3);
        ushort4 pk;
        pk.x = f2b(e0); pk.y = f2b(e1); pk.z = f2b(e2); pk.w = f2b(e3);
        *(ushort4*)&Ps[(s * 64 + w * 16 + cq) * 72 + mt * 16 + g * 4] = pk;
      }
      rs += __shfl_xor(rs, 16);
      rs += __shfl_xor(rs, 32);
      lrow[s] = lrow[s] * al + rs;
#pragma unroll
      for (int dmt = 0; dmt < 8; ++dmt) {
        o[s][dmt][0] *= al; o[s][dmt][1] *= al;
        o[s][dmt][2] *= al; o[s][dmt][3] *= al;
      }
    }

    __builtin_amdgcn_s_setprio(1);
#pragma unroll
    for (int ks = 0; ks < 2; ++ks) {
      bf16x8 pf0, pf1;
      if (nA) __builtin_memcpy(&pf0, &Ps[(w * 16 + cq) * 72 + ks * 32 + g * 8], 16);
      __builtin_memcpy(&pf1, &Ps[(64 + w * 16 + cq) * 72 + ks * 32 + g * 8], 16);
#pragma unroll
      for (int dmt = 0; dmt < 8; ++dmt) {
        bf16x8 vf;
        int slot = (ks * 4 + g) ^ (cq & 7);
        __builtin_memcpy(&vf, &Vt[(dmt * 16 + cq) * 64 + slot * 8], 16);
        if (nA)
          o[0][dmt] = __builtin_amdgcn_mfma_f32_16x16x32_bf16(vf, pf0, o[0][dmt], 0, 0, 0);
        o[1][dmt] = __builtin_amdgcn_mfma_f32_16x16x32_bf16(vf, pf1, o[1][dmt], 0, 0, 0);
      }
    }
    __builtin_amdgcn_s_setprio(0);
  }

#pragma unroll
  for (int s = 0; s < 2; ++s) {
    float inv = 1.0f / lrow[s];
    int qg = q0s[s] + w * 16 + cq;
    size_t base = ((size_t)(b * 2048 + qg)) * 2048 + h * 128;
#pragma unroll
    for (int dmt = 0; dmt < 8; ++dmt) {
      ushort4 t;
      t.x = f2b(o[s][dmt][0] * inv);
      t.y = f2b(o[s][dmt][1] * inv);
      t.z = f2b(o[s][dmt][2] * inv);
      t.w = f2b(o[s][dmt][3] * inv);
      *(ushort4*)(oh + base + dmt * 16 + g * 4) = t;
    }
  }
}

extern "C" void kernel_launch(void* const* d_in, const int* in_sizes, int n_in,
                              void* d_out, int out_size, void* d_ws, size_t ws_size,
                              hipStream_t stream) {
  (void)in_sizes; (void)n_in; (void)out_size; (void)ws_size;
  const float* query = (const float*)d_in[0];
  const float* W_qkv = (const float*)d_in[1];
  const float* b_qkv = (const float*)d_in[2];
  const float* W_out = (const float*)d_in[3];
  const float* b_out = (const float*)d_in[4];
  float* out = (float*)d_out;
  char* ws = (char*)d_ws;

  u16*    Abf  = (u16*)(ws + 0);                    // 16 MB  query bf16
  u16*    W1bf = (u16*)(ws + (size_t)16777216);     // 24 MB  W_qkv bf16
  u16*    W2bf = (u16*)(ws + (size_t)41943040);     //  8 MB  W_out bf16
  u16*    qhp  = (u16*)(ws + (size_t)50331648);     // 16 MB  (B*H,L,128) pre-scaled
  u16*    khp  = (u16*)(ws + (size_t)67108864);     // 16 MB  (B*H,L,128)
  u16*    vhT  = (u16*)(ws + (size_t)83886080);     // 16 MB  (B*H,128,L)
  u16*    ohp  = (u16*)(ws + (size_t)100663296);    // 16 MB  attn out (B,L,2048)
  float2* tab  = (float2*)(ws + (size_t)117440512); //  1 MB  rope cos/sin

  convert_all<<<24576, 256, 0, stream>>>((const float4*)query, (const float4*)W_qkv,
                                         (const float4*)W_out, (ushort4*)ws);
  rope_tab<<<512, 256, 0, stream>>>(tab);
  gemm_qkv<<<dim3(24, 16), 512, 0, stream>>>(Abf, W1bf, b_qkv, tab, qhp, khp, vhT);
  attn_flash<<<dim3(16, 32), 256, 0, stream>>>(qhp, khp, vhT, ohp);
  gemm_bt<<<dim3(16, 32), 256, 0, stream>>>(ohp, W2bf, b_out, out, 4096, 2048, 2048);
}

// Round 3
// 375.879 us; speedup vs baseline: 1.1213x; 1.1078x over previous
//
#include <hip/hip_runtime.h>

typedef unsigned short u16;
typedef unsigned int u32;
typedef __bf16 bf16x8 __attribute__((ext_vector_type(8)));
typedef float f32x4 __attribute__((ext_vector_type(4)));

__device__ __forceinline__ u16 f2b(float f) {
  u32 u = __float_as_uint(f);
  u32 r = (u + 0x7fffu + ((u >> 16) & 1u)) >> 16;
  return (u16)r;
}
__device__ __forceinline__ float b2f(u16 v) {
  return __uint_as_float(((u32)v) << 16);
}

// ---------------- fused fp32 -> bf16 cast of query, W_qkv, W_out ----------------
__global__ __launch_bounds__(256) void convert_all(
    const float4* __restrict__ q, const float4* __restrict__ w1,
    const float4* __restrict__ w2, ushort4* __restrict__ out) {
  int i = blockIdx.x * 256 + threadIdx.x;  // < 6291456
  float4 f;
  if (i < 2097152) f = q[i];
  else if (i < 5242880) f = w1[i - 2097152];
  else f = w2[i - 5242880];
  ushort4 o;
  o.x = f2b(f.x); o.y = f2b(f.y); o.z = f2b(f.z); o.w = f2b(f.w);
  out[i] = o;
}

// ---------------- RoPE cos/sin table: tab[l*64+dp] = (cos, sin) ----------------
__global__ __launch_bounds__(256) void rope_tab(float2* __restrict__ tab) {
  int idx = blockIdx.x * 256 + threadIdx.x;  // 131072 = 2048*64
  int l = idx >> 6, dp = idx & 63;
  float inv = exp2f(-(float)dp * 0.20762050593046869f);  // log2(10000)/64
  float ang = (float)l * inv;
  float s, c;
  sincosf(ang, &s, &c);
  tab[idx] = make_float2(c, s);
}

// ---------------- GEMM1 + fused RoPE/head-split/V-transpose epilogue ----------
// Round-0 known-good structure (141 us, 730 TF): 128x128 tile, 4 blocks/CU TLP.
__global__ __launch_bounds__(256) void gemm_qkv(
    const u16* __restrict__ A, const u16* __restrict__ B,
    const float* __restrict__ bias, const float2* __restrict__ tab,
    u16* __restrict__ qh, u16* __restrict__ kh, u16* __restrict__ vhT) {
  __shared__ __align__(16) u16 sh[16512];  // As(8192) | Bs(8192); epi: T stride 129
  u16* As = sh;
  u16* Bs = sh + 8192;
  const int K = 2048;
  const int tid = threadIdx.x;
  const int lane = tid & 63;
  const int wave = tid >> 6;
  const int m0 = blockIdx.y * 128;
  const int n0 = blockIdx.x * 128;
  const int wm = (wave & 1) * 64;
  const int wn = (wave >> 1) * 64;
  f32x4 acc[4][4] = {};

  const int srow = wave * 32 + (lane >> 3);
  const int scb = ((lane & 7) ^ (lane >> 3)) * 16;
  const int fr = lane & 15;
  const int g = lane >> 4;

  for (int kt = 0; kt < 32; ++kt) {
    const int k0 = kt << 6;
    __syncthreads();
    {
      const char* gA = (const char*)A + ((size_t)(m0 + srow) * K + k0) * 2 + scb;
      const char* gB = (const char*)B + ((size_t)(n0 + srow) * K + k0) * 2 + scb;
#pragma unroll
      for (int i = 0; i < 4; ++i) {
        __builtin_amdgcn_global_load_lds(
            (__attribute__((address_space(1))) void*)(gA + (size_t)i * 8 * K * 2),
            (__attribute__((address_space(3))) void*)(As + (wave * 32 + i * 8) * 64),
            16, 0, 0);
        __builtin_amdgcn_global_load_lds(
            (__attribute__((address_space(1))) void*)(gB + (size_t)i * 8 * K * 2),
            (__attribute__((address_space(3))) void*)(Bs + (wave * 32 + i * 8) * 64),
            16, 0, 0);
      }
    }
    __syncthreads();
#pragma unroll
    for (int ks = 0; ks < 2; ++ks) {
      const int so = ((ks * 4 + g) ^ (fr & 7)) * 8;
      bf16x8 aF[4], bF[4];
#pragma unroll
      for (int mi = 0; mi < 4; ++mi)
        __builtin_memcpy(&aF[mi], &As[(wm + mi * 16 + fr) * 64 + so], 16);
#pragma unroll
      for (int ni = 0; ni < 4; ++ni)
        __builtin_memcpy(&bF[ni], &Bs[(wn + ni * 16 + fr) * 64 + so], 16);
#pragma unroll
      for (int mi = 0; mi < 4; ++mi)
#pragma unroll
        for (int ni = 0; ni < 4; ++ni)
          acc[mi][ni] = __builtin_amdgcn_mfma_f32_16x16x32_bf16(aF[mi], bF[ni], acc[mi][ni], 0, 0, 0);
    }
  }

  // ---- epilogue: acc -> LDS tile T (bf16, stride 129) ----
  __syncthreads();  // all waves done reading As/Bs before overwrite
  const int rq = (lane >> 4) * 4;
  const int cq = lane & 15;
#pragma unroll
  for (int mi = 0; mi < 4; ++mi) {
#pragma unroll
    for (int ni = 0; ni < 4; ++ni) {
      int c = wn + ni * 16 + cq;
      float bs = bias[n0 + c];
#pragma unroll
      for (int i = 0; i < 4; ++i) {
        int r = wm + mi * 16 + rq + i;
        sh[r * 129 + c] = f2b(acc[mi][ni][i] + bs);
      }
    }
  }
  __syncthreads();

  const int t = n0 >> 7;       // 0..47
  const int h = t & 15;
  const int bq = m0 >> 11;     // batch (M = B*L, 2048 each)
  const int l0 = m0 & 2047;
  const int bh = bq * 16 + h;

  if (t < 32) {
    // q or k head tile: RoPE rows. 128 rows x 64 pairs, 32 iters.
    const float qs = (t < 16) ? 0.08838834764831845f : 1.0f;
    u16* dst = (t < 16) ? qh : kh;
#pragma unroll 4
    for (int it = 0; it < 32; ++it) {
      int idx = it * 256 + tid;
      int l = idx >> 6, dp = idx & 63;
      float2 cs = tab[(size_t)(l0 + l) * 64 + dp];
      float x1 = b2f(sh[l * 129 + dp]);
      float x2 = b2f(sh[l * 129 + dp + 64]);
      size_t o = ((size_t)bh * 2048 + l0 + l) * 128;
      dst[o + dp]      = f2b((x1 * cs.x - x2 * cs.y) * qs);
      dst[o + dp + 64] = f2b((x2 * cs.x + x1 * cs.y) * qs);
    }
  } else {
    // v head tile: transposed store vhT[bh*128+d][l]. 128 d x 64 l-pairs.
#pragma unroll 4
    for (int it = 0; it < 32; ++it) {
      int idx = it * 256 + tid;
      int d = idx >> 6, l2 = (idx & 63) * 2;
      ushort2 t2;
      t2.x = sh[l2 * 129 + d];
      t2.y = sh[(l2 + 1) * 129 + d];
      *(ushort2*)(vhT + ((size_t)bh * 128 + d) * 2048 + l0 + l2) = t2;
    }
  }
}

// ---------------- GEMM2: out[M,N] = A[M,K] * B[N,K]^T + bias (fp32 out) -------
__global__ __launch_bounds__(256) void gemm_bt(
    const u16* __restrict__ A, const u16* __restrict__ B,
    const float* __restrict__ bias, float* __restrict__ C,
    int M, int N, int K) {
  __shared__ __align__(16) u16 As[128 * 64];
  __shared__ __align__(16) u16 Bs[128 * 64];
  const int tid = threadIdx.x;
  const int lane = tid & 63;
  const int wave = tid >> 6;
  const int m0 = blockIdx.y * 128;
  const int n0 = blockIdx.x * 128;
  const int wm = (wave & 1) * 64;
  const int wn = (wave >> 1) * 64;
  f32x4 acc[4][4] = {};

  const int srow = wave * 32 + (lane >> 3);
  const int scb = ((lane & 7) ^ (lane >> 3)) * 16;
  const int fr = lane & 15;
  const int g = lane >> 4;

  const int kiters = K >> 6;
  for (int kt = 0; kt < kiters; ++kt) {
    const int k0 = kt << 6;
    __syncthreads();
    {
      const char* gA = (const char*)A + ((size_t)(m0 + srow) * K + k0) * 2 + scb;
      const char* gB = (const char*)B + ((size_t)(n0 + srow) * K + k0) * 2 + scb;
#pragma unroll
      for (int i = 0; i < 4; ++i) {
        __builtin_amdgcn_global_load_lds(
            (__attribute__((address_space(1))) void*)(gA + (size_t)i * 8 * K * 2),
            (__attribute__((address_space(3))) void*)(As + (wave * 32 + i * 8) * 64),
            16, 0, 0);
        __builtin_amdgcn_global_load_lds(
            (__attribute__((address_space(1))) void*)(gB + (size_t)i * 8 * K * 2),
            (__attribute__((address_space(3))) void*)(Bs + (wave * 32 + i * 8) * 64),
            16, 0, 0);
      }
    }
    __syncthreads();
#pragma unroll
    for (int ks = 0; ks < 2; ++ks) {
      const int so = ((ks * 4 + g) ^ (fr & 7)) * 8;
      bf16x8 aF[4], bF[4];
#pragma unroll
      for (int mi = 0; mi < 4; ++mi)
        __builtin_memcpy(&aF[mi], &As[(wm + mi * 16 + fr) * 64 + so], 16);
#pragma unroll
      for (int ni = 0; ni < 4; ++ni)
        __builtin_memcpy(&bF[ni], &Bs[(wn + ni * 16 + fr) * 64 + so], 16);
#pragma unroll
      for (int mi = 0; mi < 4; ++mi)
#pragma unroll
        for (int ni = 0; ni < 4; ++ni)
          acc[mi][ni] = __builtin_amdgcn_mfma_f32_16x16x32_bf16(aF[mi], bF[ni], acc[mi][ni], 0, 0, 0);
    }
  }
  const int rq = (lane >> 4) * 4;
  const int cq = lane & 15;
#pragma unroll
  for (int mi = 0; mi < 4; ++mi) {
#pragma unroll
    for (int ni = 0; ni < 4; ++ni) {
      int col = n0 + wn + ni * 16 + cq;
      float bs = bias[col];
#pragma unroll
      for (int i = 0; i < 4; ++i) {
        int row = m0 + wm + mi * 16 + rq + i;
        C[(size_t)row * N + col] = acc[mi][ni][i] + bs;
      }
    }
  }
}

// ---------------- causal flash attention, S^T orientation ----------------
// Grid: 512 blocks, 1-D. XCD-clustering remap: all 16 p-blocks of one head land
// on one XCD (bid%8 == bh%8 under round-robin dispatch) -> 4 heads/XCD = 4 MB
// K/V footprint, L2-resident. Split staging waits: vmcnt(4) (K done, V in
// flight) before QK^T; vmcnt(0) before PV -> V latency hides under QK+softmax.
__global__ __launch_bounds__(256, 2) void attn_flash(
    const u16* __restrict__ qh, const u16* __restrict__ kh,
    const u16* __restrict__ vhT, u16* __restrict__ oh) {
  __shared__ __align__(16) u16 Ks[64 * 128];
  __shared__ __align__(16) u16 Vt[128 * 64];
  __shared__ __align__(16) u16 Ps[128 * 72];
  const int tid = threadIdx.x;
  const int lane = tid & 63;
  const int w = tid >> 6;
  const int cq = lane & 15;
  const int g = lane >> 4;
  const int bid = blockIdx.x;        // 0..511
  const int j = bid >> 3;            // 0..63
  const int bh = (bid & 7) + (j & 3) * 8;  // head cluster: bh%8 == bid%8
  const int p = j >> 2;              // 0..15
  const int b = bh >> 4, h = bh & 15;
  const int ktiles = 32 - p;
  int q0s[2];
  q0s[0] = p * 64;
  q0s[1] = (31 - p) * 64;

  bf16x8 qf[2][4];
#pragma unroll
  for (int s = 0; s < 2; ++s) {
    const u16* qp = qh + ((size_t)bh * 2048 + q0s[s] + w * 16 + cq) * 128 + g * 8;
#pragma unroll
    for (int ks = 0; ks < 4; ++ks)
      __builtin_memcpy(&qf[s][ks], qp + ks * 32, 16);
  }

  f32x4 o[2][8] = {};
  float mrow[2] = {-1e30f, -1e30f};
  float lrow[2] = {0.0f, 0.0f};

  const int krl = lane >> 4;
  const int kcl = lane & 15;
  const int vrl = lane >> 3;
  const int vcl = lane & 7;

  for (int kt = 0; kt < ktiles; ++kt) {
    __syncthreads();  // prev-tile Ks/Vt reads done before restage
    {
      const size_t kvb = (size_t)bh * 2048 + (size_t)kt * 64;
#pragma unroll
      for (int i = 0; i < 4; ++i) {
        int row = w * 16 + i * 4 + krl;
        int cgl = kcl ^ (row & 7);
        const char* src = (const char*)(kh + (kvb + row) * 128 + cgl * 8);
        __builtin_amdgcn_global_load_lds(
            (__attribute__((address_space(1))) void*)src,
            (__attribute__((address_space(3))) void*)(Ks + (w * 16 + i * 4) * 128),
            16, 0, 0);
      }
#pragma unroll
      for (int i = 0; i < 4; ++i) {
        int row = w * 32 + i * 8 + vrl;
        int cgl = vcl ^ (row & 7);
        const char* src =
            (const char*)(vhT + ((size_t)bh * 128 + row) * 2048 + kt * 64 + cgl * 8);
        __builtin_amdgcn_global_load_lds(
            (__attribute__((address_space(1))) void*)src,
            (__attribute__((address_space(3))) void*)(Vt + (w * 32 + i * 8) * 64),
            16, 0, 0);
      }
    }
    // K's 4 loads done; V's 4 remain in flight (hidden under QK^T + softmax)
    asm volatile("s_waitcnt vmcnt(4)" ::: "memory");
    __builtin_amdgcn_s_barrier();
    __builtin_amdgcn_sched_barrier(0);

    const bool nA = (kt <= p);
    f32x4 S[4][2] = {};
    __builtin_amdgcn_s_setprio(1);
#pragma unroll
    for (int ks = 0; ks < 4; ++ks) {
#pragma unroll
      for (int mt = 0; mt < 4; ++mt) {
        bf16x8 kf;
        int slot = (ks * 4 + g) ^ (cq & 7);
        __builtin_memcpy(&kf, &Ks[(mt * 16 + cq) * 128 + slot * 8], 16);
        if (nA)
          S[mt][0] = __builtin_amdgcn_mfma_f32_16x16x32_bf16(kf, qf[0][ks], S[mt][0], 0, 0, 0);
        S[mt][1] = __builtin_amdgcn_mfma_f32_16x16x32_bf16(kf, qf[1][ks], S[mt][1], 0, 0, 0);
      }
    }
    __builtin_amdgcn_s_setprio(0);

#pragma unroll
    for (int s = 0; s < 2; ++s) {
      if (s == 0 && !nA) continue;
      const int dtile = s ? (ktiles - 1) : p;
      if (kt == dtile) {
        const int qg = q0s[s] + w * 16 + cq;
#pragma unroll
        for (int mt = 0; mt < 4; ++mt)
#pragma unroll
          for (int i = 0; i < 4; ++i)
            if (kt * 64 + mt * 16 + g * 4 + i > qg) S[mt][s][i] = -1e30f;
      }
      float mx = S[0][s][0];
#pragma unroll
      for (int mt = 0; mt < 4; ++mt)
#pragma unroll
        for (int i = 0; i < 4; ++i) mx = fmaxf(mx, S[mt][s][i]);
      mx = fmaxf(mx, __shfl_xor(mx, 16));
      mx = fmaxf(mx, __shfl_xor(mx, 32));
      float mnew = fmaxf(mrow[s], mx);
      float al = __expf(mrow[s] - mnew);
      mrow[s] = mnew;
      float rs = 0.0f;
#pragma unroll
      for (int mt = 0; mt < 4; ++mt) {
        float e0 = __expf(S[mt][s][0] - mnew);
        float e1 = __expf(S[mt][s][1] - mnew);
        float e2 = __expf(S[mt][s][2] - mnew);
        float e3 = __expf(S[mt][s][3] - mnew);
        rs += (e0 + e1) + (e2 + e3);
        ushort4 pk;
        pk.x = f2b(e0); pk.y = f2b(e1); pk.z = f2b(e2); pk.w = f2b(e3);
        *(ushort4*)&Ps[(s * 64 + w * 16 + cq) * 72 + mt * 16 + g * 4] = pk;
      }
      rs += __shfl_xor(rs, 16);
      rs += __shfl_xor(rs, 32);
      lrow[s] = lrow[s] * al + rs;
#pragma unroll
      for (int dmt = 0; dmt < 8; ++dmt) {
        o[s][dmt][0] *= al; o[s][dmt][1] *= al;
        o[s][dmt][2] *= al; o[s][dmt][3] *= al;
      }
    }

    // V fully landed in Vt before PV reads it
    asm volatile("s_waitcnt vmcnt(0)" ::: "memory");
    __builtin_amdgcn_s_barrier();
    __builtin_amdgcn_sched_barrier(0);

    __builtin_amdgcn_s_setprio(1);
#pragma unroll
    for (int ks = 0; ks < 2; ++ks) {
      bf16x8 pf0, pf1;
      if (nA) __builtin_memcpy(&pf0, &Ps[(w * 16 + cq) * 72 + ks * 32 + g * 8], 16);
      __builtin_memcpy(&pf1, &Ps[(64 + w * 16 + cq) * 72 + ks * 32 + g * 8], 16);
#pragma unroll
      for (int dmt = 0; dmt < 8; ++dmt) {
        bf16x8 vf;
        int slot = (ks * 4 + g) ^ (cq & 7);
        __builtin_memcpy(&vf, &Vt[(dmt * 16 + cq) * 64 + slot * 8], 16);
        if (nA)
          o[0][dmt] = __builtin_amdgcn_mfma_f32_16x16x32_bf16(vf, pf0, o[0][dmt], 0, 0, 0);
        o[1][dmt] = __builtin_amdgcn_mfma_f32_16x16x32_bf16(vf, pf1, o[1][dmt], 0, 0, 0);
      }
    }
    __builtin_amdgcn_s_setprio(0);
  }

#pragma unroll
  for (int s = 0; s < 2; ++s) {
    float inv = 1.0f / lrow[s];
    int qg = q0s[s] + w * 16 + cq;
    size_t base = ((size_t)(b * 2048 + qg)) * 2048 + h * 128;
#pragma unroll
    for (int dmt = 0; dmt < 8; ++dmt) {
      ushort4 t;
      t.x = f2b(o[s][dmt][0] * inv);
      t.y = f2b(o[s][dmt][1] * inv);
      t.z = f2b(o[s][dmt][2] * inv);
      t.w = f2b(o[s][dmt][3] * inv);
      *(ushort4*)(oh + base + dmt * 16 + g * 4) = t;
    }
  }
}

extern "C" void kernel_launch(void* const* d_in, const int* in_sizes, int n_in,
                              void* d_out, int out_size, void* d_ws, size_t ws_size,
                              hipStream_t stream) {
  (void)in_sizes; (void)n_in; (void)out_size; (void)ws_size;
  const float* query = (const float*)d_in[0];
  const float* W_qkv = (const float*)d_in[1];
  const float* b_qkv = (const float*)d_in[2];
  const float* W_out = (const float*)d_in[3];
  const float* b_out = (const float*)d_in[4];
  float* out = (float*)d_out;
  char* ws = (char*)d_ws;

  u16*    Abf  = (u16*)(ws + 0);                    // 16 MB  query bf16
  u16*    W1bf = (u16*)(ws + (size_t)16777216);     // 24 MB  W_qkv bf16
  u16*    W2bf = (u16*)(ws + (size_t)41943040);     //  8 MB  W_out bf16
  u16*    qhp  = (u16*)(ws + (size_t)50331648);     // 16 MB  (B*H,L,128) pre-scaled
  u16*    khp  = (u16*)(ws + (size_t)67108864);     // 16 MB  (B*H,L,128)
  u16*    vhT  = (u16*)(ws + (size_t)83886080);     // 16 MB  (B*H,128,L)
  u16*    ohp  = (u16*)(ws + (size_t)100663296);    // 16 MB  attn out (B,L,2048)
  float2* tab  = (float2*)(ws + (size_t)117440512); //  1 MB  rope cos/sin

  convert_all<<<24576, 256, 0, stream>>>((const float4*)query, (const float4*)W_qkv,
                                         (const float4*)W_out, (ushort4*)ws);
  rope_tab<<<512, 256, 0, stream>>>(tab);
  gemm_qkv<<<dim3(48, 32), 256, 0, stream>>>(Abf, W1bf, b_qkv, tab, qhp, khp, vhT);
  attn_flash<<<dim3(512), 256, 0, stream>>>(qhp, khp, vhT, ohp);
  gemm_bt<<<dim3(16, 32), 256, 0, stream>>>(ohp, W2bf, b_out, out, 4096, 2048, 2048);
}